// Round 1
// baseline (79.044 us; speedup 1.0000x reference)
//
#include <hip/hip_runtime.h>
#include <stdint.h>

// NMU forward: y[b,o] = prod_d( clip(M[d,o],0,1)*x[b,d] + 1-clip(M[d,o],0,1) )
// B=16384, D=256, O=32, fp32.
//
// V12 = zero-LDS, zero-sync restructure ("full-d-per-wave"):
//  - wave owns an o-HALF (16 o's) and ALL of d for 8 rows.
//    lane = oq(0..3)*16 + ds(0..15); thread owns d = ds*16..ds*16+15 and
//    o = h*16 + oq*4 .. +3  -> resident clamped M = 32 v2f = 64 VGPRs.
//  - x read DIRECTLY from global per row (4x float4 per thread; the wave's
//    16 distinct float4 @ stride 64B = 8x128B lines/instr, same line count
//    as the old staged load; the sibling o-half wave in the same block hits
//    L1 on the dup read). Software-pipelined one row ahead.
//  - d-reduction entirely on the VALU pipe via a 16-lane DPP tree:
//    quad_perm xor1 (0xB1), xor2 (0x4E), ROW_HALF_MIRROR (0x141),
//    ROW_MIRROR (0x140). After 4 levels every lane has the full product;
//    ds==0 lanes store y DIRECTLY (float4) -- no partials, no merge,
//    no __syncthreads, no LDS at all.

typedef float v2f __attribute__((ext_vector_type(2)));

constexpr int D = 256;
constexpr int O = 32;
constexpr int WROWS = 8;            // rows per wave; block = 4 waves = 16 rows

template <int CTRL>
__device__ __forceinline__ float dppmul(float v) {
    int i = __builtin_bit_cast(int, v);
    int p = __builtin_amdgcn_update_dpp(i, i, CTRL, 0xF, 0xF, false);
    return v * __builtin_bit_cast(float, p);
}
template <int CTRL>
__device__ __forceinline__ v2f dppmul2(v2f v) {
    v2f r; r.x = dppmul<CTRL>(v.x); r.y = dppmul<CTRL>(v.y); return r;
}
__device__ __forceinline__ v2f clamp01(v2f v) {
    v = __builtin_elementwise_max(v, (v2f)0.0f);
    return __builtin_elementwise_min(v, (v2f)1.0f);
}
// t = m*(x-1)+1  ==  m*x + (1-m); "+1" stays an inline constant.
#define TERM(mm, e) __builtin_elementwise_fma((mm), (v2f){(e), (e)}, (v2f){1.0f, 1.0f})

__global__ __launch_bounds__(256, 4)
void nmu_fwd(const float* __restrict__ x, const float* __restrict__ M,
             float* __restrict__ y)
{
    const int tid  = threadIdx.x;
    const int lane = tid & 63;
    const int wv   = tid >> 6;
    const int ds   = lane & 15;          // d-chunk: d = ds*16 + dd (low bits -> DPP rows)
    const int oq   = lane >> 4;          // o-quad within the half
    const int h    = wv & 1;             // o-half (0: o 0..15, 1: o 16..31)
    const int rg   = wv >> 1;            // row group within block
    const int row0 = blockIdx.x * (2 * WROWS) + rg * WROWS;
    const int o0   = h * 16 + oq * 4;    // this thread's 4 o's

    // ---- resident clamped M: one float4 per dd (16-B aligned since o0%4==0)
    const float4* M4 = reinterpret_cast<const float4*>(M);
    const int mb = ds * 16 * (O / 4) + (o0 >> 2);  // float4 index; per-dd stride O/4
#define MLOAD(dd) \
    float4 mv##dd = M4[mb + (dd) * (O / 4)];                      \
    v2f mL##dd = clamp01((v2f){mv##dd.x, mv##dd.y});              \
    v2f mH##dd = clamp01((v2f){mv##dd.z, mv##dd.w});
    MLOAD(0)  MLOAD(1)  MLOAD(2)  MLOAD(3)
    MLOAD(4)  MLOAD(5)  MLOAD(6)  MLOAD(7)
    MLOAD(8)  MLOAD(9)  MLOAD(10) MLOAD(11)
    MLOAD(12) MLOAD(13) MLOAD(14) MLOAD(15)
#undef MLOAD

    // ---- x addressing: this thread's 16 floats of each row = 4 x float4
    const float4* xbase = reinterpret_cast<const float4*>(x + (size_t)row0 * D) + ds * 4;
    // row stride in float4 units:
    constexpr int RS4 = D / 4;

    // software pipeline: row r+1's loads issue before row r's compute
    float4 a0 = xbase[0], a1 = xbase[1], a2 = xbase[2], a3 = xbase[3];

#pragma unroll 1
    for (int r = 0; r < WROWS; ++r) {
        const int rn = (r + 1) & (WROWS - 1);          // last iter reloads row 0 (L1 hit, discarded)
        const float4* xn = xbase + rn * RS4;
        float4 b0 = xn[0], b1 = xn[1], b2 = xn[2], b3 = xn[3];

        const float e0  = a0.x - 1.0f, e1  = a0.y - 1.0f, e2  = a0.z - 1.0f, e3  = a0.w - 1.0f;
        const float e4  = a1.x - 1.0f, e5  = a1.y - 1.0f, e6  = a1.z - 1.0f, e7  = a1.w - 1.0f;
        const float e8  = a2.x - 1.0f, e9  = a2.y - 1.0f, e10 = a2.z - 1.0f, e11 = a2.w - 1.0f;
        const float e12 = a3.x - 1.0f, e13 = a3.y - 1.0f, e14 = a3.z - 1.0f, e15 = a3.w - 1.0f;

        v2f pL = (TERM(mL0,  e0)  * TERM(mL1,  e1))  * (TERM(mL2,  e2)  * TERM(mL3,  e3));
        pL    *= (TERM(mL4,  e4)  * TERM(mL5,  e5))  * (TERM(mL6,  e6)  * TERM(mL7,  e7));
        pL    *= (TERM(mL8,  e8)  * TERM(mL9,  e9))  * (TERM(mL10, e10) * TERM(mL11, e11));
        pL    *= (TERM(mL12, e12) * TERM(mL13, e13)) * (TERM(mL14, e14) * TERM(mL15, e15));

        v2f pH = (TERM(mH0,  e0)  * TERM(mH1,  e1))  * (TERM(mH2,  e2)  * TERM(mH3,  e3));
        pH    *= (TERM(mH4,  e4)  * TERM(mH5,  e5))  * (TERM(mH6,  e6)  * TERM(mH7,  e7));
        pH    *= (TERM(mH8,  e8)  * TERM(mH9,  e9))  * (TERM(mH10, e10) * TERM(mH11, e11));
        pH    *= (TERM(mH12, e12) * TERM(mH13, e13)) * (TERM(mH14, e14) * TERM(mH15, e15));

        // product across the 16 ds-lanes (two interleaved dependency chains)
        pL = dppmul2<0xB1>(pL);  pH = dppmul2<0xB1>(pH);   // xor 1
        pL = dppmul2<0x4E>(pL);  pH = dppmul2<0x4E>(pH);   // xor 2
        pL = dppmul2<0x141>(pL); pH = dppmul2<0x141>(pH);  // half-row mirror
        pL = dppmul2<0x140>(pL); pH = dppmul2<0x140>(pH);  // row mirror

        if (ds == 0) {                                     // 4 lanes/wave store final y
            float4 out = {pL.x, pL.y, pH.x, pH.y};
            *reinterpret_cast<float4*>(y + (size_t)(row0 + r) * O + o0) = out;
        }

        a0 = b0; a1 = b1; a2 = b2; a3 = b3;
    }
}

extern "C" void kernel_launch(void* const* d_in, const int* in_sizes, int n_in,
                              void* d_out, int out_size, void* d_ws, size_t ws_size,
                              hipStream_t stream) {
    const float* x = (const float*)d_in[0];   // [16384, 256]
    const float* M = (const float*)d_in[1];   // [256, 32]
    float* y = (float*)d_out;                 // [16384, 32]
    const int B = in_sizes[0] / D;            // 16384
    dim3 grid(B / (2 * WROWS));               // 1024 blocks = 4 per CU
    nmu_fwd<<<grid, 256, 0, stream>>>(x, M, y);
}

// Round 2
// 72.794 us; speedup vs baseline: 1.0859x; 1.0859x over previous
//
#include <hip/hip_runtime.h>
#include <stdint.h>

// NMU forward: y[b,o] = prod_d( clip(M[d,o],0,1)*x[b,d] + 1-clip(M[d,o],0,1) )
// B=16384, D=256, O=32, fp32.
//
// R13 = R11 (staged-LDS, DPP reduce) + three VALU cuts. V12's direct-global
// experiment regressed +5.7us: 8x lane-request amplification on the VMEM/L1
// path (duplication is only free on the LDS broadcast port). Reverted.
//
// Structure (R11): lane = (oq 0..7)*8 + (ds 0..7); wave w owns d-quarter;
// thread owns 8 d's x 4 o's. x tile (16 rows x 1 KB) staged coalesced to LDS;
// compute does 2 ds_read_b128 per row per wave.
//
// R13 changes:
//  - resident c = 1-m alongside m (64 const VGPRs): t = fma(m, x, c) kills
//    the 8 per-row x-1 subs.
//  - DPP butterfly stops after xor1+xor2 (quad products): lanes ds in {0,4}
//    store 8 quarter-partials/row; merge epilogue multiplies 8 (was 4).
//    -8 VALU/row in the hot loop for +4 loads/+4 muls once per thread.
//  - manual 1-row prefetch of the two ds_read_b128.

typedef float v2f __attribute__((ext_vector_type(2)));

constexpr int D = 256;
constexpr int O = 32;
constexpr int ROWS_PB = 16;              // rows per block -> 1024 blocks

template <int CTRL>
__device__ __forceinline__ float dppmul(float v) {
    int i = __builtin_bit_cast(int, v);
    int p = __builtin_amdgcn_update_dpp(i, i, CTRL, 0xF, 0xF, false);
    return v * __builtin_bit_cast(float, p);
}
template <int CTRL>
__device__ __forceinline__ v2f dppmul2(v2f v) {
    v2f r; r.x = dppmul<CTRL>(v.x); r.y = dppmul<CTRL>(v.y); return r;
}
__device__ __forceinline__ v2f clamp01(v2f v) {
    v = __builtin_elementwise_max(v, (v2f)0.0f);
    return __builtin_elementwise_min(v, (v2f)1.0f);
}
// t = m*x + (1-m) = fma(m, x, c) with resident c
#define T(mm, cc, xx) __builtin_elementwise_fma((mm), (v2f){(xx), (xx)}, (cc))

__global__ __launch_bounds__(256, 4)
void nmu_fwd(const float* __restrict__ x, const float* __restrict__ M,
             float* __restrict__ y)
{
    __shared__ __align__(16) float xt[ROWS_PB * D];          // 16 KB x tile
    __shared__ __align__(16) float part[ROWS_PB * 8 * O];    // 16 KB partials
    const int tid  = threadIdx.x;
    const int lane = tid & 63;
    const int w    = tid >> 6;       // wave = d-quarter
    const int ds   = lane & 7;       // 8-d subslice (low bits -> DPP quads)
    const int oq   = lane >> 3;      // o-quad
    const int row0 = blockIdx.x * ROWS_PB;

    // ---- stage x tile: 4 independent 1KB-coalesced f4 loads per thread ----
    const float4* xg = reinterpret_cast<const float4*>(x + row0 * D);
    float4 s0 = xg[tid], s1 = xg[256 + tid], s2 = xg[512 + tid], s3 = xg[768 + tid];

    // ---- resident clamped M and c = 1-M: d = w*64+ds*8+dd, o = oq*4..+3 ----
    const float2* M2 = reinterpret_cast<const float2*>(M);
    const int mb = (w * 64 + ds * 8) * (O / 2) + oq * 2;     // float2 index
#define MLOAD(dd) \
    float2 l##dd = M2[mb + (dd) * 16]; float2 h##dd = M2[mb + (dd) * 16 + 1]; \
    v2f mL##dd = clamp01((v2f){l##dd.x, l##dd.y});                            \
    v2f mH##dd = clamp01((v2f){h##dd.x, h##dd.y});                            \
    v2f cL##dd = (v2f){1.0f, 1.0f} - mL##dd;                                  \
    v2f cH##dd = (v2f){1.0f, 1.0f} - mH##dd;
    MLOAD(0) MLOAD(1) MLOAD(2) MLOAD(3) MLOAD(4) MLOAD(5) MLOAD(6) MLOAD(7)
#undef MLOAD

    float4* lp = reinterpret_cast<float4*>(xt);
    lp[tid] = s0; lp[256 + tid] = s1; lp[512 + tid] = s2; lp[768 + tid] = s3;
    __syncthreads();

    // ---- per row: 2 ds_read_b128 (prefetched), 8 d-terms x 4 o, 2-level
    //      DPP quad reduce, predicated b128 partial write ----
    const int xoff = w * 16 + ds * 2;                        // f4 idx in row
    const float4* lt = reinterpret_cast<const float4*>(xt);
    float4 xa = lt[xoff], xb = lt[xoff + 1];
#pragma unroll 1
    for (int r = 0; r < ROWS_PB; ++r) {
        const int rn = (r + 1) & (ROWS_PB - 1);              // last iter: dummy reload
        float4 na = lt[rn * 64 + xoff];
        float4 nb = lt[rn * 64 + xoff + 1];

        v2f pL = (T(mL0, cL0, xa.x) * T(mL1, cL1, xa.y)) * (T(mL2, cL2, xa.z) * T(mL3, cL3, xa.w));
        pL    *= (T(mL4, cL4, xb.x) * T(mL5, cL5, xb.y)) * (T(mL6, cL6, xb.z) * T(mL7, cL7, xb.w));
        v2f pH = (T(mH0, cH0, xa.x) * T(mH1, cH1, xa.y)) * (T(mH2, cH2, xa.z) * T(mH3, cH3, xa.w));
        pH    *= (T(mH4, cH4, xb.x) * T(mH5, cH5, xb.y)) * (T(mH6, cH6, xb.z) * T(mH7, cH7, xb.w));

        // product within each 4-lane quad: xor1, xor2 (quads never straddle oq)
        pL = dppmul2<0xB1>(pL); pL = dppmul2<0x4E>(pL);
        pH = dppmul2<0xB1>(pH); pH = dppmul2<0x4E>(pH);

        if ((ds & 3) == 0) {                                 // lanes ds=0,4: 16/wave
            const int sub = ds >> 2;                         // quarter-half id
            float4 pv = {pL.x, pL.y, pH.x, pH.y};
            *reinterpret_cast<float4*>(&part[((r * 4 + w) * 2 + sub) * O + oq * 4]) = pv;
        }
        xa = na; xb = nb;
    }
    __syncthreads();

    // ---- merge 8 partials; 256 threads = 16 rows x 16 o-pairs ----
    {
        const int mr = tid >> 4;
        const int op = tid & 15;
        const v2f* pp = reinterpret_cast<const v2f*>(part);
        const int base = mr * 8 * (O / 2) + op;
        v2f a = pp[base +  0] * pp[base + 16];
        v2f b = pp[base + 32] * pp[base + 48];
        v2f c = pp[base + 64] * pp[base + 80];
        v2f d = pp[base + 96] * pp[base + 112];
        a = (a * b) * (c * d);
        *reinterpret_cast<v2f*>(y + (row0 + mr) * O + op * 2) = a;  // 8B/lane
    }
}

extern "C" void kernel_launch(void* const* d_in, const int* in_sizes, int n_in,
                              void* d_out, int out_size, void* d_ws, size_t ws_size,
                              hipStream_t stream) {
    const float* x = (const float*)d_in[0];   // [16384, 256]
    const float* M = (const float*)d_in[1];   // [256, 32]
    float* y = (float*)d_out;                 // [16384, 32]
    const int B = in_sizes[0] / D;            // 16384
    dim3 grid(B / ROWS_PB);                   // 1024 blocks = 4 per CU
    nmu_fwd<<<grid, 256, 0, stream>>>(x, M, y);
}